// Round 7
// baseline (362.035 us; speedup 1.0000x reference)
//
#include <hip/hip_runtime.h>
#include <hip/hip_bf16.h>

// Problem constants
#define Bsz 4
#define Tseq 2048
#define Cdim 1024
#define NH 16
#define HD 64
#define Mrows (Bsz*Tseq)      // 8192
#define N3C (3*Cdim)          // 3072

typedef __attribute__((ext_vector_type(8))) short short8;
typedef __attribute__((ext_vector_type(4))) short short4v;
typedef __attribute__((ext_vector_type(4))) float float4v;

__device__ __forceinline__ unsigned short f2b(float f) {
    union { float f; unsigned u; } x; x.f = f;
    unsigned u = x.u;
    u += 0x7fff + ((u >> 16) & 1);   // true RNE to bf16
    return (unsigned short)(u >> 16);
}

__device__ __forceinline__ float lo_b(unsigned u) {
    union { unsigned x; float f; } c; c.x = u << 16; return c.f;
}
__device__ __forceinline__ float hi_b(unsigned u) {
    union { unsigned x; float f; } c; c.x = u & 0xffff0000u; return c.f;
}

// pack 2 floats -> bf16x2 dword (RNE)
__device__ __forceinline__ unsigned pk2bf(float a, float b) {
#if __has_builtin(__builtin_amdgcn_cvt_pk_bf16_f32)
    auto w = __builtin_amdgcn_cvt_pk_bf16_f32(a, b);
    unsigned u; __builtin_memcpy(&u, &w, 4);
    return u;
#else
    return (unsigned)f2b(a) | ((unsigned)f2b(b) << 16);
#endif
}

// async global->LDS, 16B per lane; lds dst must be wave-uniform (HW adds lane*16)
#define GLDS(gp, lp) __builtin_amdgcn_global_load_lds(                         \
    (const __attribute__((address_space(1))) unsigned*)(gp),                   \
    (__attribute__((address_space(3))) unsigned*)(lp), 16, 0, 0)

// ---------------- cast x: f32 -> bf16 ----------------
__global__ __launch_bounds__(256) void cast_kernel(const float* __restrict__ in,
                                                   unsigned short* __restrict__ out, int n) {
    int i = (blockIdx.x * 256 + threadIdx.x) * 4;
    if (i < n) {
        float4 v = *reinterpret_cast<const float4*>(in + i);
        ushort4 o;
        o.x = f2b(v.x); o.y = f2b(v.y); o.z = f2b(v.z); o.w = f2b(v.w);
        *reinterpret_cast<ushort4*>(out + i) = o;
    }
}

// ---------------- transpose + cast: W[K][N] f32 -> Wt[N][K] bf16 ----------------
__global__ __launch_bounds__(256) void transpose_cast(const float* __restrict__ in,
                                                      unsigned short* __restrict__ out,
                                                      int K, int N) {
    __shared__ float tile[32][33];
    int n0 = blockIdx.x * 32, k0 = blockIdx.y * 32;
    int tx = threadIdx.x & 31, ty = threadIdx.x >> 5;   // 8 rows per pass
    #pragma unroll
    for (int i = 0; i < 32; i += 8)
        tile[ty + i][tx] = in[(k0 + ty + i) * N + n0 + tx];
    __syncthreads();
    #pragma unroll
    for (int i = 0; i < 32; i += 8)
        out[(size_t)(n0 + ty + i) * K + k0 + tx] = f2b(tile[tx][ty + i]);
}

// ---------------- bf16 MFMA GEMM: C[M,N] = A[M,K] * Bt[N,K]^T ----------------
// 128x128 tile, BK=64 (half the barriers of BK=32), global_load_lds staging.
// LDS rows chunk-staggered (+8 shorts per 8 rows) to spread frag-read banks.
// XCD-panel swizzle: XCD x owns row-blocks [8x,8x+8) x all cols.

#define GROW(r) ((r) * 64 + ((r) >> 3) * 8)   // staggered LDS row base (shorts)

template<bool QKV, int NCOL>
__global__ __launch_bounds__(256) void gemm_bt(const unsigned short* __restrict__ A,
                                               const unsigned short* __restrict__ Bt,
                                               const float* __restrict__ bias,
                                               unsigned short* __restrict__ qb,
                                               unsigned short* __restrict__ kb,
                                               unsigned short* __restrict__ vb,
                                               float* __restrict__ out) {
    __shared__ unsigned short As[8320];
    __shared__ unsigned short Bs[8320];
    int tid = threadIdx.x;
    int lane = tid & 63, wave = tid >> 6;
    int wm = wave >> 1, wn = wave & 1;
    int l15 = lane & 15, quad = lane >> 4;

    // XCD-panel swizzle (blocks dispatch round-robin to XCDs by flat id % 8)
    int f = blockIdx.x;
    int xcd = f & 7, slot = f >> 3;
    int rowblk = xcd * 8 + (slot & 7);   // 64 row-blocks: 8 per XCD
    int colblk = slot >> 3;              // 0..NCOL-1
    int row0 = rowblk * 128;
    int col0 = colblk * 128;

    // staging: wave w covers rows [w*32, w*32+32), 4 chunks of 8 rows;
    // lane l -> row +(l>>3), col (l&7)*8 (16B)
    const unsigned short* Ag = A + (size_t)(row0 + wave * 32 + (lane >> 3)) * Cdim + (lane & 7) * 8;
    const unsigned short* Bg = Bt + (size_t)(col0 + wave * 32 + (lane >> 3)) * Cdim + (lane & 7) * 8;
    unsigned short* Al = &As[wave * 2080];   // per-chunk c: +c*520
    unsigned short* Bl = &Bs[wave * 2080];

    float4v acc[4][4] = {};

    for (int k0 = 0; k0 < Cdim; k0 += 64) {
        __syncthreads();
        #pragma unroll
        for (int c = 0; c < 4; c++) {
            GLDS(Ag + k0 + (size_t)(c * 8) * Cdim, Al + c * 520);
            GLDS(Bg + k0 + (size_t)(c * 8) * Cdim, Bl + c * 520);
        }
        __syncthreads();   // drains vmcnt -> staged data visible to all waves

        #pragma unroll
        for (int g = 0; g < 2; g++) {
            short8 af[4], bf[4];
            #pragma unroll
            for (int mi = 0; mi < 4; mi++)
                af[mi] = *(const short8*)&As[GROW(wm * 64 + mi * 16 + l15) + g * 32 + quad * 8];
            #pragma unroll
            for (int ni = 0; ni < 4; ni++)
                bf[ni] = *(const short8*)&Bs[GROW(wn * 64 + ni * 16 + l15) + g * 32 + quad * 8];
            #pragma unroll
            for (int mi = 0; mi < 4; mi++)
                #pragma unroll
                for (int ni = 0; ni < 4; ni++)
                    acc[mi][ni] = __builtin_amdgcn_mfma_f32_16x16x32_bf16(af[mi], bf[ni], acc[mi][ni], 0, 0, 0);
        }
    }

    // epilogue
    #pragma unroll
    for (int mi = 0; mi < 4; mi++) {
        #pragma unroll
        for (int ni = 0; ni < 4; ni++) {
            int colb = col0 + wn * 64 + ni * 16 + l15;
            int rowb = row0 + wm * 64 + mi * 16 + quad * 4;
            if (QKV) {
                int p = colb >> 10;          // 0=q 1=k 2=v
                int h = (colb & 1023) >> 6;
                int d = colb & 63;
                int b = rowb >> 11;
                int t = rowb & 2047;
                if (p == 2) {
                    // V transposed [bh][d][T]: r-values are t-consecutive -> ushort4
                    ushort4 pk;
                    pk.x = f2b(acc[mi][ni][0] + bias[colb]);
                    pk.y = f2b(acc[mi][ni][1] + bias[colb]);
                    pk.z = f2b(acc[mi][ni][2] + bias[colb]);
                    pk.w = f2b(acc[mi][ni][3] + bias[colb]);
                    *(ushort4*)&vb[((size_t)(b * NH + h) * HD + d) * Tseq + t] = pk;
                } else {
                    unsigned short* dst = (p == 0) ? qb : kb;
                    #pragma unroll
                    for (int r = 0; r < 4; r++)
                        dst[((size_t)(b * NH + h) * Tseq + (t + r)) * HD + d] =
                            f2b(acc[mi][ni][r] + bias[colb]);
                }
            } else {
                #pragma unroll
                for (int r = 0; r < 4; r++)
                    out[(size_t)(rowb + r) * Cdim + colb] = acc[mi][ni][r] + bias[colb];
            }
        }
    }
}

// ---------------- flash attention (causal), bf16 MFMA, BARRIER-FREE ----------------
// block = 128 thr (2 waves); block = one 64-row q-tile (32 rows/wave).
// K staged per-WAVE via global_load_lds (no __syncthreads anywhere);
// V B-frags loaded directly from pre-transposed global V (no LDS for V).
// S^T register trick: S^T C-layout == A-operand layout of mfma 16x16x16bf16.

__global__ __launch_bounds__(128, 3) void attn_kernel(const unsigned short* __restrict__ qb,
                                                      const unsigned short* __restrict__ kb,
                                                      const unsigned short* __restrict__ vt,
                                                      unsigned short* __restrict__ yb) {
    __shared__ unsigned short Ks[2][64 * 64];   // per-wave [key][d], 8KB each

    int tid = threadIdx.x;
    int lane = tid & 63, wave = tid >> 6;      // 2 waves
    int l15 = lane & 15, quad = lane >> 4;
    int bh = blockIdx.x;                       // head id (fast dim -> XCD grouping)
    int qt = 31 - blockIdx.y;                  // heavy q-tiles dispatch first

    const unsigned short* Qh = qb + (size_t)bh * Tseq * HD;
    const unsigned short* Kh = kb + (size_t)bh * Tseq * HD;
    const unsigned short* Vh = vt + (size_t)bh * HD * Tseq;
    int b = bh >> 4, h = bh & 15;
    const float cexp = 0.18033688011112042f;   // 0.125 * log2(e)

    int q0 = qt * 64;
    int rb0 = q0 + wave * 32;                  // this wave's 32 q-rows

    // Q fragments (B-operand layout: lane holds Q[qrow=l15][d=quad*8+j])
    short8 qf[2][2];
    #pragma unroll
    for (int mi = 0; mi < 2; mi++)
        #pragma unroll
        for (int g = 0; g < 2; g++)
            qf[mi][g] = *(const short8*)(Qh + (size_t)(rb0 + mi * 16 + l15) * HD + g * 32 + quad * 8);

    // per-wave K staging: lane l -> key +(l>>3), d (l&7)*8
    const unsigned short* Kg = Kh + (size_t)(lane >> 3) * HD + (lane & 7) * 8;
    unsigned short* Kl = &Ks[wave][0];
    // V frag base: row = dg*16+l15 (d), col = kg*16+quad*4 (key)
    const unsigned short* Vg = Vh + (size_t)l15 * Tseq + quad * 4;

    float4v ov[2][4] = {};                 // O accs: [16-row blk][d=dg*16+l15], row=quad*4+r
    float m[2]  = {-1e30f, -1e30f};        // running row max (qrow = l15)
    float lp[2] = {0.f, 0.f};              // running row sum of p~ (qrow = l15)
    int ntiles = qt + 1;

    for (int jt = 0; jt < ntiles; jt++) {
        int j0 = jt * 64;
        // wave's previous ds_reads all consumed by MFMAs already; drain LDS queue
        // before DMA overwrites the buffer, then stage K tile (wave-private)
        asm volatile("s_waitcnt lgkmcnt(0)" ::: "memory");
        #pragma unroll
        for (int c = 0; c < 8; c++)
            GLDS(Kg + (size_t)(j0 + c * 8) * HD, Kl + c * 512);

        // V B-frags straight from global (L2-resident after first q-block)
        short4v vf[4][4];
        #pragma unroll
        for (int dg = 0; dg < 4; dg++)
            #pragma unroll
            for (int kg = 0; kg < 4; kg++)
                vf[dg][kg] = *(const short4v*)(Vg + (size_t)(dg * 16) * Tseq + j0 + kg * 16);

        asm volatile("s_waitcnt vmcnt(0)" ::: "memory");   // K staged, V in regs

        // S^T = K * Q^T  (C-layout: row=key=quad*4+r, col=qrow=l15) — raw scores
        float4v st[2][4];
        #pragma unroll
        for (int mi = 0; mi < 2; mi++)
            #pragma unroll
            for (int kg = 0; kg < 4; kg++)
                st[mi][kg] = (float4v){0.f, 0.f, 0.f, 0.f};
        #pragma unroll
        for (int g = 0; g < 2; g++) {
            #pragma unroll
            for (int kg = 0; kg < 4; kg++) {
                short8 kf = *(const short8*)&Kl[(kg * 16 + l15) * 64 + g * 32 + quad * 8];
                st[0][kg] = __builtin_amdgcn_mfma_f32_16x16x32_bf16(kf, qf[0][g], st[0][kg], 0, 0, 0);
                st[1][kg] = __builtin_amdgcn_mfma_f32_16x16x32_bf16(kf, qf[1][g], st[1][kg], 0, 0, 0);
            }
        }

        // causal mask: only the diagonal tile needs it
        if (jt == ntiles - 1) {
            #pragma unroll
            for (int mi = 0; mi < 2; mi++) {
                int qrow = rb0 + mi * 16 + l15;
                #pragma unroll
                for (int kg = 0; kg < 4; kg++) {
                    int keyb = j0 + kg * 16 + quad * 4;
                    #pragma unroll
                    for (int r = 0; r < 4; r++)
                        if (keyb + r > qrow) st[mi][kg][r] = -1e30f;
                }
            }
        }

        // online softmax with row-max (row = qrow = l15 for st)
        short4v pf[2][4];
        #pragma unroll
        for (int mi = 0; mi < 2; mi++) {
            float mx = st[mi][0][0];
            #pragma unroll
            for (int kg = 0; kg < 4; kg++)
                #pragma unroll
                for (int r = 0; r < 4; r++)
                    mx = fmaxf(mx, st[mi][kg][r]);
            mx = fmaxf(mx, __shfl_xor(mx, 16));
            mx = fmaxf(mx, __shfl_xor(mx, 32));
            float mn = fmaxf(m[mi], mx);
            // rescale only when some row's max actually grew (skips most late tiles)
            if (__any(mn > m[mi])) {
                float alv = __builtin_amdgcn_exp2f((m[mi] - mn) * cexp);
                m[mi] = mn;
                lp[mi] *= alv;
                float ar_[4];
                #pragma unroll
                for (int r = 0; r < 4; r++)
                    ar_[r] = __shfl(alv, quad * 4 + r);
                #pragma unroll
                for (int dg = 0; dg < 4; dg++)
                    #pragma unroll
                    for (int r = 0; r < 4; r++)
                        ov[mi][dg][r] *= ar_[r];
            }
            float sum = 0.f;
            #pragma unroll
            for (int kg = 0; kg < 4; kg++) {
                float p0 = __builtin_amdgcn_exp2f((st[mi][kg][0] - m[mi]) * cexp);
                float p1 = __builtin_amdgcn_exp2f((st[mi][kg][1] - m[mi]) * cexp);
                float p2 = __builtin_amdgcn_exp2f((st[mi][kg][2] - m[mi]) * cexp);
                float p3 = __builtin_amdgcn_exp2f((st[mi][kg][3] - m[mi]) * cexp);
                unsigned u0 = pk2bf(p0, p1);
                unsigned u1 = pk2bf(p2, p3);
                // l from ROUNDED p: numerator/denominator consistent
                sum += (lo_b(u0) + hi_b(u0)) + (lo_b(u1) + hi_b(u1));
                union { unsigned u[2]; short4v s; } pk_;
                pk_.u[0] = u0; pk_.u[1] = u1;
                pf[mi][kg] = pk_.s;
            }
            lp[mi] += sum;
        }

        // O += P * V   (A = P^T frags from regs, B = V frags from regs)
        #pragma unroll
        for (int kg = 0; kg < 4; kg++) {
            #pragma unroll
            for (int dg = 0; dg < 4; dg++) {
                ov[0][dg] = __builtin_amdgcn_mfma_f32_16x16x16bf16_1k(pf[0][kg], vf[dg][kg], ov[0][dg], 0, 0, 0);
                ov[1][dg] = __builtin_amdgcn_mfma_f32_16x16x16bf16_1k(pf[1][kg], vf[dg][kg], ov[1][dg], 0, 0, 0);
            }
        }
    }

    // epilogue: reduce l across quads, divide, store y[b][t][h*64+d]
    #pragma unroll
    for (int mi = 0; mi < 2; mi++) {
        float lf = lp[mi];
        lf += __shfl_xor(lf, 16);
        lf += __shfl_xor(lf, 32);          // all lanes: full sum for qrow = l15
        float rinv[4];
        #pragma unroll
        for (int r = 0; r < 4; r++)
            rinv[r] = 1.0f / __shfl(lf, quad * 4 + r);
        #pragma unroll
        for (int dg = 0; dg < 4; dg++)
            #pragma unroll
            for (int r = 0; r < 4; r++) {
                int t = rb0 + mi * 16 + quad * 4 + r;
                yb[((size_t)b * Tseq + t) * Cdim + h * HD + dg * 16 + l15] =
                    f2b(ov[mi][dg][r] * rinv[r]);
            }
    }
}

extern "C" void kernel_launch(void* const* d_in, const int* in_sizes, int n_in,
                              void* d_out, int out_size, void* d_ws, size_t ws_size,
                              hipStream_t stream) {
    const float* x  = (const float*)d_in[0];
    const float* Wa = (const float*)d_in[1];
    const float* ba = (const float*)d_in[2];
    const float* Wp = (const float*)d_in[3];
    const float* bp = (const float*)d_in[4];
    float* out = (float*)d_out;

    unsigned short* ws = (unsigned short*)d_ws;
    unsigned short* xb  = ws;                          // 8192*1024
    unsigned short* Wat = xb  + (size_t)Mrows * Cdim;  // 3072*1024
    unsigned short* Wpt = Wat + (size_t)N3C * Cdim;    // 1024*1024
    unsigned short* qb  = Wpt + (size_t)Cdim * Cdim;   // [bh][T][HD]
    unsigned short* kb  = qb  + (size_t)Bsz * NH * Tseq * HD;   // [bh][T][HD]
    unsigned short* vb  = kb  + (size_t)Bsz * NH * Tseq * HD;   // [bh][HD][T]  (transposed)
    unsigned short* yb  = vb  + (size_t)Bsz * NH * Tseq * HD;

    int nx = Mrows * Cdim;
    cast_kernel<<<nx / 4 / 256, 256, 0, stream>>>(x, xb, nx);
    transpose_cast<<<dim3(N3C / 32, Cdim / 32), 256, 0, stream>>>(Wa, Wat, Cdim, N3C);
    transpose_cast<<<dim3(Cdim / 32, Cdim / 32), 256, 0, stream>>>(Wp, Wpt, Cdim, Cdim);

    gemm_bt<true, 24><<<64 * 24, 256, 0, stream>>>(
        xb, Wat, ba, qb, kb, vb, nullptr);

    attn_kernel<<<dim3(Bsz * NH, 32), 128, 0, stream>>>(qb, kb, vb, yb);

    gemm_bt<false, 8><<<64 * 8, 256, 0, stream>>>(
        yb, Wpt, bp, nullptr, nullptr, nullptr, out);
}

// Round 8
// 290.253 us; speedup vs baseline: 1.2473x; 1.2473x over previous
//
#include <hip/hip_runtime.h>
#include <hip/hip_bf16.h>

// Problem constants
#define Bsz 4
#define Tseq 2048
#define Cdim 1024
#define NH 16
#define HD 64
#define Mrows (Bsz*Tseq)      // 8192
#define N3C (3*Cdim)          // 3072

typedef __attribute__((ext_vector_type(8))) short short8;
typedef __attribute__((ext_vector_type(4))) short short4v;
typedef __attribute__((ext_vector_type(4))) float float4v;

__device__ __forceinline__ unsigned short f2b(float f) {
    union { float f; unsigned u; } x; x.f = f;
    unsigned u = x.u;
    u += 0x7fff + ((u >> 16) & 1);   // true RNE to bf16
    return (unsigned short)(u >> 16);
}

// pack 2 floats -> bf16x2 dword (RNE)
__device__ __forceinline__ unsigned pk2bf(float a, float b) {
#if __has_builtin(__builtin_amdgcn_cvt_pk_bf16_f32)
    auto w = __builtin_amdgcn_cvt_pk_bf16_f32(a, b);
    unsigned u; __builtin_memcpy(&u, &w, 4);
    return u;
#else
    return (unsigned)f2b(a) | ((unsigned)f2b(b) << 16);
#endif
}

// async global->LDS, 16B per lane; lds dst must be wave-uniform (HW adds lane*16)
#define GLDS(gp, lp) __builtin_amdgcn_global_load_lds(                         \
    (const __attribute__((address_space(1))) unsigned*)(gp),                   \
    (__attribute__((address_space(3))) unsigned*)(lp), 16, 0, 0)

// ---------------- cast x: f32 -> bf16 ----------------
__global__ __launch_bounds__(256) void cast_kernel(const float* __restrict__ in,
                                                   unsigned short* __restrict__ out, int n) {
    int i = (blockIdx.x * 256 + threadIdx.x) * 4;
    if (i < n) {
        float4 v = *reinterpret_cast<const float4*>(in + i);
        ushort4 o;
        o.x = f2b(v.x); o.y = f2b(v.y); o.z = f2b(v.z); o.w = f2b(v.w);
        *reinterpret_cast<ushort4*>(out + i) = o;
    }
}

// ---------------- transpose + cast: W[K][N] f32 -> Wt[N][K] bf16 ----------------
__global__ __launch_bounds__(256) void transpose_cast(const float* __restrict__ in,
                                                      unsigned short* __restrict__ out,
                                                      int K, int N) {
    __shared__ float tile[32][33];
    int n0 = blockIdx.x * 32, k0 = blockIdx.y * 32;
    int tx = threadIdx.x & 31, ty = threadIdx.x >> 5;   // 8 rows per pass
    #pragma unroll
    for (int i = 0; i < 32; i += 8)
        tile[ty + i][tx] = in[(k0 + ty + i) * N + n0 + tx];
    __syncthreads();
    #pragma unroll
    for (int i = 0; i < 32; i += 8)
        out[(size_t)(n0 + ty + i) * K + k0 + tx] = f2b(tile[tx][ty + i]);
}

// ---------------- bf16 MFMA GEMM: C[M,N] = A[M,K] * Bt[N,K]^T ----------------
// 128x128 tile, BK=64, global_load_lds staging, chunk-staggered LDS rows.
// XCD-panel swizzle: XCD x owns row-blocks [8x,8x+8) x all cols.

#define GROW(r) ((r) * 64 + ((r) >> 3) * 8)   // staggered LDS row base (shorts)

template<bool QKV, int NCOL>
__global__ __launch_bounds__(256) void gemm_bt(const unsigned short* __restrict__ A,
                                               const unsigned short* __restrict__ Bt,
                                               const float* __restrict__ bias,
                                               unsigned short* __restrict__ qb,
                                               unsigned short* __restrict__ kb,
                                               unsigned short* __restrict__ vb,
                                               float* __restrict__ out) {
    __shared__ unsigned short As[8320];
    __shared__ unsigned short Bs[8320];
    int tid = threadIdx.x;
    int lane = tid & 63, wave = tid >> 6;
    int wm = wave >> 1, wn = wave & 1;
    int l15 = lane & 15, quad = lane >> 4;

    // XCD-panel swizzle (blocks dispatch round-robin to XCDs by flat id % 8)
    int f = blockIdx.x;
    int xcd = f & 7, slot = f >> 3;
    int rowblk = xcd * 8 + (slot & 7);   // 64 row-blocks: 8 per XCD
    int colblk = slot >> 3;              // 0..NCOL-1
    int row0 = rowblk * 128;
    int col0 = colblk * 128;

    // staging: wave w covers rows [w*32, w*32+32), 4 chunks of 8 rows;
    // lane l -> row +(l>>3), col (l&7)*8 (16B)
    const unsigned short* Ag = A + (size_t)(row0 + wave * 32 + (lane >> 3)) * Cdim + (lane & 7) * 8;
    const unsigned short* Bg = Bt + (size_t)(col0 + wave * 32 + (lane >> 3)) * Cdim + (lane & 7) * 8;
    unsigned short* Al = &As[wave * 2080];   // per-chunk c: +c*520
    unsigned short* Bl = &Bs[wave * 2080];

    float4v acc[4][4] = {};

    for (int k0 = 0; k0 < Cdim; k0 += 64) {
        __syncthreads();
        #pragma unroll
        for (int c = 0; c < 4; c++) {
            GLDS(Ag + k0 + (size_t)(c * 8) * Cdim, Al + c * 520);
            GLDS(Bg + k0 + (size_t)(c * 8) * Cdim, Bl + c * 520);
        }
        __syncthreads();   // drains vmcnt -> staged data visible to all waves

        #pragma unroll
        for (int g = 0; g < 2; g++) {
            short8 af[4], bf[4];
            #pragma unroll
            for (int mi = 0; mi < 4; mi++)
                af[mi] = *(const short8*)&As[GROW(wm * 64 + mi * 16 + l15) + g * 32 + quad * 8];
            #pragma unroll
            for (int ni = 0; ni < 4; ni++)
                bf[ni] = *(const short8*)&Bs[GROW(wn * 64 + ni * 16 + l15) + g * 32 + quad * 8];
            #pragma unroll
            for (int mi = 0; mi < 4; mi++)
                #pragma unroll
                for (int ni = 0; ni < 4; ni++)
                    acc[mi][ni] = __builtin_amdgcn_mfma_f32_16x16x32_bf16(af[mi], bf[ni], acc[mi][ni], 0, 0, 0);
        }
    }

    // epilogue
    #pragma unroll
    for (int mi = 0; mi < 4; mi++) {
        #pragma unroll
        for (int ni = 0; ni < 4; ni++) {
            int colb = col0 + wn * 64 + ni * 16 + l15;
            int rowb = row0 + wm * 64 + mi * 16 + quad * 4;
            if (QKV) {
                int p = colb >> 10;          // 0=q 1=k 2=v
                int h = (colb & 1023) >> 6;
                int d = colb & 63;
                int b = rowb >> 11;
                int t = rowb & 2047;
                if (p == 2) {
                    // V transposed [bh][d][T]: r-values are t-consecutive -> ushort4
                    ushort4 pk;
                    pk.x = f2b(acc[mi][ni][0] + bias[colb]);
                    pk.y = f2b(acc[mi][ni][1] + bias[colb]);
                    pk.z = f2b(acc[mi][ni][2] + bias[colb]);
                    pk.w = f2b(acc[mi][ni][3] + bias[colb]);
                    *(ushort4*)&vb[((size_t)(b * NH + h) * HD + d) * Tseq + t] = pk;
                } else {
                    unsigned short* dst = (p == 0) ? qb : kb;
                    #pragma unroll
                    for (int r = 0; r < 4; r++)
                        dst[((size_t)(b * NH + h) * Tseq + (t + r)) * HD + d] =
                            f2b(acc[mi][ni][r] + bias[colb]);
                }
            } else {
                #pragma unroll
                for (int r = 0; r < 4; r++)
                    out[(size_t)(rowb + r) * Cdim + colb] = acc[mi][ni][r] + bias[colb];
            }
        }
    }
}

// ---------------- flash attention (causal), bf16 MFMA ----------------
// block = 128 thr (2 waves); one 64-row q-tile per block (32 rows/wave).
// 128-key staging windows (two 64-key compute halves per barrier pair).
// K and V staged via global_load_lds into XOR-swizzled LDS (16B granule
// swizzle cg^(row&7)): conflict-free frag reads AND contiguous DMA dst.
// S^T register trick: S^T C-layout == A-operand of mfma 16x16x16bf16_1k.

__global__ __launch_bounds__(128, 3) void attn_kernel(const unsigned short* __restrict__ qb,
                                                      const unsigned short* __restrict__ kb,
                                                      const unsigned short* __restrict__ vt,
                                                      unsigned short* __restrict__ yb) {
    __shared__ unsigned short Ks[2][64 * 64];   // [half][key][64d], swizzled
    __shared__ unsigned short Vs[2][64 * 64];   // [half][d][64key], swizzled

    int tid = threadIdx.x;
    int lane = tid & 63, wave = tid >> 6;      // 2 waves
    int l15 = lane & 15, quad = lane >> 4;
    int bh = blockIdx.x;                       // head id (fast dim -> XCD grouping)
    int qt = 31 - blockIdx.y;                  // heavy q-tiles dispatch first

    const unsigned short* Qh = qb + (size_t)bh * Tseq * HD;
    const unsigned short* Kh = kb + (size_t)bh * Tseq * HD;
    const unsigned short* Vh = vt + (size_t)bh * HD * Tseq;
    int b = bh >> 4, h = bh & 15;
    const float cexp = 0.18033688011112042f;   // 0.125 * log2(e)

    int q0 = qt * 64;
    int rb0 = q0 + wave * 32;                  // this wave's 32 q-rows

    // Q fragments (B-operand layout: lane holds Q[qrow=l15][d=quad*8+j])
    short8 qf[2][2];
    #pragma unroll
    for (int mi = 0; mi < 2; mi++)
        #pragma unroll
        for (int g = 0; g < 2; g++)
            qf[mi][g] = *(const short8*)(Qh + (size_t)(rb0 + mi * 16 + l15) * HD + g * 32 + quad * 8);

    // staging lane mapping: row offset (lane>>3), swizzled source granule
    int srow = lane >> 3;                       // 0..7
    int scol = ((lane & 7) ^ srow) * 8;         // source col (shorts), 16B granule
    // frag-read swizzle constants
    int sx = l15 & 7;
    int kx0 = ((0 * 4 + quad) ^ sx) * 8;        // K frag col, g=0
    int kx1 = ((1 * 4 + quad) ^ sx) * 8;        // K frag col, g=1
    int qh_ = quad >> 1, ql_ = quad & 1;

    float4v ov[2][4] = {};                 // O accs: [16-row blk][d=dg*16+l15], row=quad*4+r
    float m[2]  = {-1e30f, -1e30f};        // running row max (qrow = l15)
    float lp[2] = {0.f, 0.f};              // running row sum of p (qrow = l15)

    for (int j0 = 0; j0 <= q0; j0 += 128) {
        __syncthreads();
        {   // this wave stages half 'wave' (keys j0+wave*64 .. +64) of K and V
            int jb = j0 + wave * 64;
            const unsigned short* Kg = Kh + (size_t)(jb + srow) * HD + scol;
            const unsigned short* Vg = Vh + (size_t)srow * Tseq + jb + scol;
            unsigned short* Kl = &Ks[wave][0];
            unsigned short* Vl = &Vs[wave][0];
            #pragma unroll
            for (int cc = 0; cc < 8; cc++) {
                GLDS(Kg + (size_t)(cc * 8) * HD, Kl + cc * 512);
                GLDS(Vg + (size_t)(cc * 8) * Tseq, Vl + cc * 512);
            }
        }
        __syncthreads();

        int nh = (j0 + 64 <= q0) ? 2 : 1;
        #pragma unroll 1
        for (int hh = 0; hh < nh; hh++) {
            int j0h = j0 + hh * 64;
            const unsigned short* Kl = &Ks[hh][0];
            const unsigned short* Vl = &Vs[hh][0];

            // S^T = K * Q^T  (C-layout: row=key=quad*4+r, col=qrow=l15)
            float4v st[2][4];
            #pragma unroll
            for (int mi = 0; mi < 2; mi++)
                #pragma unroll
                for (int kg = 0; kg < 4; kg++)
                    st[mi][kg] = (float4v){0.f, 0.f, 0.f, 0.f};
            #pragma unroll
            for (int kg = 0; kg < 4; kg++) {
                int krow = kg * 1024 + l15 * 64;
                short8 kf0 = *(const short8*)&Kl[krow + kx0];
                short8 kf1 = *(const short8*)&Kl[krow + kx1];
                st[0][kg] = __builtin_amdgcn_mfma_f32_16x16x32_bf16(kf0, qf[0][0], st[0][kg], 0, 0, 0);
                st[0][kg] = __builtin_amdgcn_mfma_f32_16x16x32_bf16(kf1, qf[0][1], st[0][kg], 0, 0, 0);
                st[1][kg] = __builtin_amdgcn_mfma_f32_16x16x32_bf16(kf0, qf[1][0], st[1][kg], 0, 0, 0);
                st[1][kg] = __builtin_amdgcn_mfma_f32_16x16x32_bf16(kf1, qf[1][1], st[1][kg], 0, 0, 0);
            }

            // causal mask: only the diagonal half-tile needs it
            if (j0h == q0) {
                #pragma unroll
                for (int mi = 0; mi < 2; mi++) {
                    int qrow = rb0 + mi * 16 + l15;
                    #pragma unroll
                    for (int kg = 0; kg < 4; kg++) {
                        int keyb = j0h + kg * 16 + quad * 4;
                        #pragma unroll
                        for (int r = 0; r < 4; r++)
                            if (keyb + r > qrow) st[mi][kg][r] = -1e30f;
                    }
                }
            }

            // online softmax with row-max (row = qrow = l15 for st)
            short4v pf[2][4];
            #pragma unroll
            for (int mi = 0; mi < 2; mi++) {
                float mx = st[mi][0][0];
                #pragma unroll
                for (int kg = 0; kg < 4; kg++)
                    #pragma unroll
                    for (int r = 0; r < 4; r++)
                        mx = fmaxf(mx, st[mi][kg][r]);
                mx = fmaxf(mx, __shfl_xor(mx, 16));
                mx = fmaxf(mx, __shfl_xor(mx, 32));
                float mn = fmaxf(m[mi], mx);
                // rescale only when some row's max actually grew
                if (__any(mn > m[mi])) {
                    float alv = __builtin_amdgcn_exp2f((m[mi] - mn) * cexp);
                    m[mi] = mn;
                    lp[mi] *= alv;
                    float ar_[4];
                    #pragma unroll
                    for (int r = 0; r < 4; r++)
                        ar_[r] = __shfl(alv, quad * 4 + r);
                    #pragma unroll
                    for (int dg = 0; dg < 4; dg++)
                        #pragma unroll
                        for (int r = 0; r < 4; r++)
                            ov[mi][dg][r] *= ar_[r];
                }
                float mc = -m[mi] * cexp;    // exp arg = s*cexp + mc (1 fma each)
                float sum = 0.f;
                #pragma unroll
                for (int kg = 0; kg < 4; kg++) {
                    float p0 = __builtin_amdgcn_exp2f(__builtin_fmaf(st[mi][kg][0], cexp, mc));
                    float p1 = __builtin_amdgcn_exp2f(__builtin_fmaf(st[mi][kg][1], cexp, mc));
                    float p2 = __builtin_amdgcn_exp2f(__builtin_fmaf(st[mi][kg][2], cexp, mc));
                    float p3 = __builtin_amdgcn_exp2f(__builtin_fmaf(st[mi][kg][3], cexp, mc));
                    sum += (p0 + p1) + (p2 + p3);
                    union { unsigned u[2]; short4v s; } pk_;
                    pk_.u[0] = pk2bf(p0, p1);
                    pk_.u[1] = pk2bf(p2, p3);
                    pf[mi][kg] = pk_.s;
                }
                lp[mi] += sum;
            }

            // O += P * V  (A = P^T frags from regs, B = V frags from swizzled LDS)
            #pragma unroll
            for (int kg = 0; kg < 4; kg++) {
                int vx = (((kg * 2 + qh_) ^ sx) << 3) + ql_ * 4;
                #pragma unroll
                for (int dg = 0; dg < 4; dg++) {
                    short4v vf = *(const short4v*)&Vl[dg * 1024 + l15 * 64 + vx];
                    ov[0][dg] = __builtin_amdgcn_mfma_f32_16x16x16bf16_1k(pf[0][kg], vf, ov[0][dg], 0, 0, 0);
                    ov[1][dg] = __builtin_amdgcn_mfma_f32_16x16x16bf16_1k(pf[1][kg], vf, ov[1][dg], 0, 0, 0);
                }
            }
        }
    }

    // epilogue: reduce l across quads, divide, store y[b][t][h*64+d]
    #pragma unroll
    for (int mi = 0; mi < 2; mi++) {
        float lf = lp[mi];
        lf += __shfl_xor(lf, 16);
        lf += __shfl_xor(lf, 32);          // all lanes: full sum for qrow = l15
        float rinv[4];
        #pragma unroll
        for (int r = 0; r < 4; r++)
            rinv[r] = 1.0f / __shfl(lf, quad * 4 + r);
        #pragma unroll
        for (int dg = 0; dg < 4; dg++)
            #pragma unroll
            for (int r = 0; r < 4; r++) {
                int t = rb0 + mi * 16 + quad * 4 + r;
                yb[((size_t)b * Tseq + t) * Cdim + h * HD + dg * 16 + l15] =
                    f2b(ov[mi][dg][r] * rinv[r]);
            }
    }
}

extern "C" void kernel_launch(void* const* d_in, const int* in_sizes, int n_in,
                              void* d_out, int out_size, void* d_ws, size_t ws_size,
                              hipStream_t stream) {
    const float* x  = (const float*)d_in[0];
    const float* Wa = (const float*)d_in[1];
    const float* ba = (const float*)d_in[2];
    const float* Wp = (const float*)d_in[3];
    const float* bp = (const float*)d_in[4];
    float* out = (float*)d_out;

    unsigned short* ws = (unsigned short*)d_ws;
    unsigned short* xb  = ws;                          // 8192*1024
    unsigned short* Wat = xb  + (size_t)Mrows * Cdim;  // 3072*1024
    unsigned short* Wpt = Wat + (size_t)N3C * Cdim;    // 1024*1024
    unsigned short* qb  = Wpt + (size_t)Cdim * Cdim;   // [bh][T][HD]
    unsigned short* kb  = qb  + (size_t)Bsz * NH * Tseq * HD;   // [bh][T][HD]
    unsigned short* vb  = kb  + (size_t)Bsz * NH * Tseq * HD;   // [bh][HD][T]  (transposed)
    unsigned short* yb  = vb  + (size_t)Bsz * NH * Tseq * HD;

    int nx = Mrows * Cdim;
    cast_kernel<<<nx / 4 / 256, 256, 0, stream>>>(x, xb, nx);
    transpose_cast<<<dim3(N3C / 32, Cdim / 32), 256, 0, stream>>>(Wa, Wat, Cdim, N3C);
    transpose_cast<<<dim3(Cdim / 32, Cdim / 32), 256, 0, stream>>>(Wp, Wpt, Cdim, Cdim);

    gemm_bt<true, 24><<<64 * 24, 256, 0, stream>>>(
        xb, Wat, ba, qb, kb, vb, nullptr);

    attn_kernel<<<dim3(Bsz * NH, 32), 128, 0, stream>>>(qb, kb, vb, yb);

    gemm_bt<false, 8><<<64 * 8, 256, 0, stream>>>(
        yb, Wpt, bp, nullptr, nullptr, nullptr, out);
}